// Round 2
// baseline (356.281 us; speedup 1.0000x reference)
//
#include <hip/hip_runtime.h>
#include <hip/hip_bf16.h>
#include <stdint.h>

#define N_NODES  50000
#define N_GRAPHS 256
#define DIM      128
#define N_EDGES  800000
#define K2       256            // fused K = [agg | h]
#define N_STRIPS (N_NODES / 16) // 3125, exact
#define PAD_CAP  64             // max degree slack (mean 16; fixed edge list, no overflow)
#define NBUCKET  196            // ceil(50000/256) buckets of 256 nodes (bucket = dst>>8)
#define NCHUNK   256            // edge chunks
#define CHUNK    3125           // NCHUNK*CHUNK == N_EDGES exactly
#define RO_ROWS  32             // readout rows per block (occupancy fix)

typedef __attribute__((ext_vector_type(8))) short  short8;
typedef __attribute__((ext_vector_type(4))) float  floatx4;

// counted waits for the global_load_lds pipeline (rule #18: sched_barrier after)
#define WAITVM4() do { asm volatile("s_waitcnt vmcnt(4)" ::: "memory"); \
                       __builtin_amdgcn_sched_barrier(0); } while (0)
#define WAITVM0() do { asm volatile("s_waitcnt vmcnt(0)" ::: "memory"); \
                       __builtin_amdgcn_sched_barrier(0); } while (0)

__device__ __forceinline__ ushort f2bf(float f) {
    union { float f; uint32_t u; } c; c.f = f;
    uint32_t u = c.u;
    return (ushort)((u + 0x7fffu + ((u >> 16) & 1u)) >> 16);  // RNE
}
__device__ __forceinline__ float bf2f(ushort b) {
    union { uint32_t u; float f; } c; c.u = ((uint32_t)b) << 16;
    return c.f;
}

// ---------- prep: fp32 x -> bf16 ----------
__global__ __launch_bounds__(256) void k_convert_x(const float* __restrict__ x,
                                                   ushort* __restrict__ xb) {
    int i = blockIdx.x * 256 + threadIdx.x;          // float4 index
    const int n4 = N_NODES * DIM / 4;
    if (i < n4) {
        float4 v = ((const float4*)x)[i];
        uint32_t lo = (uint32_t)f2bf(v.x) | ((uint32_t)f2bf(v.y) << 16);
        uint32_t hi = (uint32_t)f2bf(v.z) | ((uint32_t)f2bf(v.w) << 16);
        ((uint2*)xb)[i] = make_uint2(lo, hi);
    }
}

// ---------- prep: all 3 layers' Wt[n][k] = bf16( k<128 ? Wl[k][n] : Wr[k-128][n] ) ----------
__global__ __launch_bounds__(256) void k_prep_w_all(const float* __restrict__ Wl0, const float* __restrict__ Wr0,
                                                    const float* __restrict__ Wl1, const float* __restrict__ Wr1,
                                                    const float* __restrict__ Wl2, const float* __restrict__ Wr2,
                                                    ushort* __restrict__ Wt) {   // 3 * DIM * K2
    int i = blockIdx.x * 256 + threadIdx.x;
    if (i < 3 * DIM * K2) {
        int layer = i / (DIM * K2);
        int j = i % (DIM * K2);
        int n = j / K2, k = j % K2;
        const float* Wl = (layer == 0) ? Wl0 : (layer == 1) ? Wl1 : Wl2;
        const float* Wr = (layer == 0) ? Wr0 : (layer == 1) ? Wr1 : Wr2;
        float v = (k < DIM) ? Wl[k * DIM + n] : Wr[(k - DIM) * DIM + n];
        Wt[i] = f2bf(v);
    }
}

// ---------- radix bucket build (no global atomics) ----------
__global__ __launch_bounds__(256) void k_hist(const int* __restrict__ dst,
                                              int* __restrict__ counts) {  // [NCHUNK][NBUCKET]
    __shared__ int hist[NBUCKET];
    int t = threadIdx.x, b = blockIdx.x;
    if (t < NBUCKET) hist[t] = 0;
    __syncthreads();
    const int e0 = b * CHUNK;
    for (int i = t; i < CHUNK; i += 256)
        atomicAdd(&hist[dst[e0 + i] >> 8], 1);
    __syncthreads();
    if (t < NBUCKET) counts[b * NBUCKET + t] = hist[t];
}

__global__ __launch_bounds__(256) void k_scan_col(const int* __restrict__ counts,
                                                  int* __restrict__ off,     // [NCHUNK][NBUCKET]
                                                  int* __restrict__ total) { // [NBUCKET]
    __shared__ int buf[256];
    int t = threadIdx.x, j = blockIdx.x;            // j < NBUCKET
    int v = counts[t * NBUCKET + j];
    buf[t] = v;
    __syncthreads();
    #pragma unroll
    for (int d = 1; d < 256; d <<= 1) {
        int x = (t >= d) ? buf[t - d] : 0;
        __syncthreads();
        buf[t] += x;
        __syncthreads();
    }
    off[t * NBUCKET + j] = buf[t] - v;              // exclusive within column
    if (t == 255) total[j] = buf[255];
}

__global__ __launch_bounds__(256) void k_scan_total(const int* __restrict__ total,
                                                    int* __restrict__ basep) {
    __shared__ int buf[256];
    int t = threadIdx.x;
    int v = (t < NBUCKET) ? total[t] : 0;
    buf[t] = v;
    __syncthreads();
    #pragma unroll
    for (int d = 1; d < 256; d <<= 1) {
        int x = (t >= d) ? buf[t - d] : 0;
        __syncthreads();
        buf[t] += x;
        __syncthreads();
    }
    if (t < NBUCKET) basep[t] = buf[t] - v;         // exclusive
}

__global__ __launch_bounds__(256) void k_scatter(const int* __restrict__ src,
                                                 const int* __restrict__ dst,
                                                 const int* __restrict__ off,
                                                 const int* __restrict__ basep,
                                                 uint32_t* __restrict__ ebuf) {
    __shared__ int cur[NBUCKET];
    int t = threadIdx.x, b = blockIdx.x;
    if (t < NBUCKET) cur[t] = off[b * NBUCKET + t] + basep[t];
    __syncthreads();
    const int e0 = b * CHUNK;
    for (int i = t; i < CHUNK; i += 256) {
        int d = dst[e0 + i];
        int s = src[e0 + i];                         // < 50000 < 2^16
        int p = atomicAdd(&cur[d >> 8], 1);
        ebuf[p] = ((uint32_t)(d & 255) << 16) | (uint32_t)s;
    }
}

__global__ __launch_bounds__(256) void k_build(const uint32_t* __restrict__ ebuf,
                                               const int* __restrict__ total,
                                               const int* __restrict__ basep,
                                               int* __restrict__ padded,
                                               int* __restrict__ cnt) {
    __shared__ int lcnt[256];
    int t = threadIdx.x, j = blockIdx.x;
    lcnt[t] = 0;
    __syncthreads();
    int b0 = basep[j], tot = total[j];
    for (int i = t; i < tot; i += 256) {
        uint32_t v = ebuf[b0 + i];
        int dl = (int)(v >> 16);
        int s  = (int)(v & 0xffffu);
        int p  = atomicAdd(&lcnt[dl], 1);
        if (p < PAD_CAP) padded[((size_t)j * 256 + dl) * PAD_CAP + p] = s;
    }
    __syncthreads();
    int node = j * 256 + t;
    if (node < N_NODES) cnt[node] = lcnt[t];
}

// ---------- canonicalize adjacency: bitonic sort each node's list across one wave ----------
__global__ __launch_bounds__(256) void k_sort_adj(int* __restrict__ padded,
                                                  const int* __restrict__ cnt) {
    int wid  = threadIdx.x >> 6;
    int lane = threadIdx.x & 63;
    int node = blockIdx.x * 4 + wid;
    if (node >= N_NODES) return;
    int deg = cnt[node];
    int m   = deg < PAD_CAP ? deg : PAD_CAP;
    int* lst = padded + (size_t)node * PAD_CAP;
    int v = (lane < m) ? lst[lane] : 0x7fffffff;   // pad sorts to the end
    #pragma unroll
    for (int k = 2; k <= 64; k <<= 1) {
        #pragma unroll
        for (int j = k >> 1; j > 0; j >>= 1) {
            int other  = __shfl_xor(v, j, 64);
            bool down  = (lane & k) != 0;
            bool lower = (lane & j) == 0;
            v = (lower ^ down) ? min(v, other) : max(v, other);
        }
    }
    if (lane < m) lst[lane] = v;                   // ascending neighbor ids
}

// ---------- per-graph node ranges from sorted batch (no atomics) ----------
__global__ __launch_bounds__(256) void k_gbounds(const int* __restrict__ batch,
                                                 int* __restrict__ gstart,
                                                 int* __restrict__ gend) {
    int i = blockIdx.x * 256 + threadIdx.x;
    if (i >= N_NODES) return;
    int g = batch[i];
    if (i == 0) gstart[g] = 0;
    int gn = (i + 1 < N_NODES) ? batch[i + 1] : -1;
    if (gn != g) {
        gend[g] = i + 1;
        if (gn >= 0) gstart[gn] = i + 1;
    }
}

// ---------- fused SAGE layer: async-DMA gather-mean into LDS, then MFMA ----------
// Phase 1: per wave, chunks of 16 neighbor rows staged into a double-buffered 4 KB
// LDS buffer via 4x global_load_lds width=16 (4 random rows per instruction:
// per-lane global addr, wave-uniform linear LDS dest). Counted s_waitcnt vmcnt(4)
// keeps the next chunk's DMA in flight while accumulating the current one from LDS
// (conflict-free ds_read_b32). No VGPR round-trip, no compiler vmcnt(0) drain.
// Phase 2: A = [LDS agg | global h] frags, B = Wt, 2 col-tiles/wave. Unchanged.
template <bool OUT_F32>
__global__ __launch_bounds__(256) void k_layer(const ushort* __restrict__ h_in,
                                               const int* __restrict__ padded,
                                               const int* __restrict__ cnt,
                                               const ushort* __restrict__ Wt,
                                               const float* __restrict__ bias,
                                               ushort* __restrict__ out_bf,
                                               float* __restrict__ out_f) {
    __shared__ uint32_t sPool[4 * 2 * 16 * 64];    // 32 KB: wave x dbuf x 16 rows x 64 dw
    __shared__ ushort   sAgg[16 * DIM];            // 4 KB
    __shared__ int      sIdx[16 * PAD_CAP];        // 4 KB neighbor lists
    __shared__ int      sCnt[16];
    __shared__ int      sChl[4][17];               // per-wave chunk list: q | (e0<<8)
    __shared__ int      sNch[4];

    int t    = threadIdx.x;
    int wid  = t >> 6;
    int lane = t & 63;
    int r0   = blockIdx.x * 16;

    // ---- stage neighbor lists + degrees (coalesced: 256 threads x int4 = 4 KB) ----
    ((int4*)sIdx)[t] = ((const int4*)(padded + (size_t)r0 * PAD_CAP))[t];
    if (t < 16) sCnt[t] = cnt[r0 + t];
    __syncthreads();

    // ---- per-wave flattened chunk list (wave-uniform; lane 0 writes) ----
    if (lane == 0) {
        int n = 0;
        #pragma unroll
        for (int q = 0; q < 4; ++q) {
            int m = min(sCnt[wid * 4 + q], PAD_CAP);
            for (int e0 = 0; e0 < m; e0 += 16)
                sChl[wid][n++] = q | (e0 << 8);
        }
        sNch[wid] = n;
    }
    // zero agg rows for isolated nodes (no chunks emitted for them)
    #pragma unroll
    for (int q = 0; q < 4; ++q) {
        int node = wid * 4 + q;
        if (sCnt[node] == 0) ((uint32_t*)(sAgg + node * DIM))[lane] = 0u;
    }
    int nch = sNch[wid];

    // ---- async-DMA double-buffered gather-mean ----
    {
        float ax[4] = {0.f, 0.f, 0.f, 0.f};
        float ay[4] = {0.f, 0.f, 0.f, 0.f};
        int   sub   = lane >> 4;                   // row-in-group 0..3
        int   boff  = (lane & 15) << 4;            // byte offset within row

        // stage(chunk cj -> buffer cj&1): 4x global_load_lds dwordx4
        auto stage = [&](int cj) {
            int ch = sChl[wid][cj];
            int q = ch & 255, e0 = ch >> 8;
            int node = wid * 4 + q;
            int m = min(sCnt[node], PAD_CAP);
            const int* lst = sIdx + node * PAD_CAP;
            uint32_t* db = sPool + ((wid * 2 + (cj & 1)) << 10);  // 1024 dwords/buf
            #pragma unroll
            for (int g = 0; g < 4; ++g) {
                int ek = e0 + g * 4 + sub;
                int id = lst[ek < m ? ek : m - 1];              // m>=1 here
                const char* gp = (const char*)h_in + ((size_t)id << 8) + boff;
                __builtin_amdgcn_global_load_lds(
                    (const __attribute__((address_space(1))) uint32_t*)gp,
                    (__attribute__((address_space(3))) uint32_t*)(db + g * 256),
                    16, 0, 0);
            }
        };

        if (nch > 0) {
            stage(0);
            for (int ci = 0; ci < nch; ++ci) {
                if (ci + 1 < nch) { stage(ci + 1); WAITVM4(); }
                else              { WAITVM0(); }
                // consume chunk ci from buffer ci&1
                int ch = sChl[wid][ci];
                int q = ch & 255, e0 = ch >> 8;
                int node = wid * 4 + q;
                int deg = sCnt[node];
                int m = min(deg, PAD_CAP);
                const uint32_t* bp = sPool + ((wid * 2 + (ci & 1)) << 10);
                #pragma unroll
                for (int k = 0; k < 16; ++k) {
                    uint32_t w = bp[k * 64 + lane];
                    if (e0 + k >= m) w = 0u;       // predicated tail (bf16 +0.0)
                    ax[k & 3] += __uint_as_float(w << 16);
                    ay[k & 3] += __uint_as_float(w & 0xffff0000u);
                }
                bool last = (ci + 1 >= nch) || ((sChl[wid][ci + 1] & 255) != q);
                if (last) {
                    float axs = (ax[0] + ax[1]) + (ax[2] + ax[3]);
                    float ays = (ay[0] + ay[1]) + (ay[2] + ay[3]);
                    float inv = 1.0f / (float)(deg > 0 ? deg : 1);
                    uint32_t o = (uint32_t)f2bf(axs * inv) | ((uint32_t)f2bf(ays * inv) << 16);
                    ((uint32_t*)(sAgg + node * DIM))[lane] = o;
                    #pragma unroll
                    for (int j = 0; j < 4; ++j) { ax[j] = 0.f; ay[j] = 0.f; }
                }
            }
        }
    }
    __syncthreads();

    // ---- phase 2: MFMA. A-frags: lane holds A[m=lane&15][k=quad*8+j] ----
    int row  = lane & 15;
    int quad = lane >> 4;
    short8 a[8];
    const ushort* srow = sAgg + row * DIM + quad * 8;
    #pragma unroll
    for (int ks = 0; ks < 4; ++ks) a[ks] = *(const short8*)(srow + ks * 32);  // LDS b128
    const ushort* hrow = h_in + (size_t)(r0 + row) * DIM + quad * 8;
    #pragma unroll
    for (int ks = 0; ks < 4; ++ks) a[4 + ks] = *(const short8*)(hrow + ks * 32);

    #pragma unroll
    for (int c = 0; c < 2; ++c) {
        int ct  = wid * 2 + c;                     // 4 waves x 2 = 8 col-tiles
        int col = ct * 16 + row;
        const ushort* wrow = Wt + (size_t)col * K2 + quad * 8;
        floatx4 acc = {0.f, 0.f, 0.f, 0.f};
        #pragma unroll
        for (int ks = 0; ks < 8; ++ks) {
            short8 b = *(const short8*)(wrow + ks * 32);
            acc = __builtin_amdgcn_mfma_f32_16x16x32_bf16(a[ks], b, acc, 0, 0, 0);
        }
        float bv = bias[col];
        #pragma unroll
        for (int r = 0; r < 4; ++r) {
            int m = r0 + quad * 4 + r;             // C/D: col=lane&15, row=quad*4+reg
            float v = acc[r] + bv;
            v = v > 0.f ? v : 0.f;
            if (OUT_F32) out_f[(size_t)m * DIM + col] = v;
            else         out_bf[(size_t)m * DIM + col] = f2bf(v);
        }
    }
}

// ---------- mean/max readout (batch sorted -> run-length flush) ----------
__global__ __launch_bounds__(128) void k_readout(const float* __restrict__ h,
                                                 const int* __restrict__ batch,
                                                 float* __restrict__ out) {
    int d  = threadIdx.x;                 // 0..127
    int n0 = blockIdx.x * RO_ROWS;
    int n1 = min(n0 + RO_ROWS, N_NODES);
    int cur = -1; float sum = 0.f, mx = 0.f;
    for (int i = n0; i < n1; ++i) {
        int g = batch[i];                 // block-uniform
        if (g != cur) {
            if (cur >= 0) {
                atomicAdd(&out[cur * 2 * DIM + d], sum);
                atomicMax((int*)&out[cur * 2 * DIM + DIM + d], __float_as_int(mx));
            }
            cur = g; sum = 0.f; mx = 0.f;
        }
        float v = h[(size_t)i * DIM + d];
        sum += v; mx = fmaxf(mx, v);
    }
    if (cur >= 0) {
        atomicAdd(&out[cur * 2 * DIM + d], sum);
        atomicMax((int*)&out[cur * 2 * DIM + DIM + d], __float_as_int(mx));
    }
}

__global__ __launch_bounds__(256) void k_finalize(float* __restrict__ out,
                                                  const int* __restrict__ gstart,
                                                  const int* __restrict__ gend) {
    int i = blockIdx.x * 256 + threadIdx.x;
    if (i < N_GRAPHS * DIM) {
        int g = i / DIM, d = i % DIM;
        int c = gend[g] - gstart[g];
        out[g * 2 * DIM + d] /= (float)(c > 0 ? c : 1);
    }
}

extern "C" void kernel_launch(void* const* d_in, const int* in_sizes, int n_in,
                              void* d_out, int out_size, void* d_ws, size_t ws_size,
                              hipStream_t stream) {
    const float* x     = (const float*)d_in[0];
    const int*   ei    = (const int*)d_in[1];
    const int*   src   = ei;
    const int*   dst   = ei + N_EDGES;
    const int*   batch = (const int*)d_in[2];
    const float* Wl[3] = {(const float*)d_in[3], (const float*)d_in[6], (const float*)d_in[9]};
    const float* bl[3] = {(const float*)d_in[4], (const float*)d_in[7], (const float*)d_in[10]};
    const float* Wr[3] = {(const float*)d_in[5], (const float*)d_in[8], (const float*)d_in[11]};
    float* out = (float*)d_out;

    char* base = (char*)d_ws;
    size_t o = 0;
    auto alloc = [&](size_t b) -> char* {
        char* p = base + o;
        o = (o + b + 255) & ~(size_t)255;
        return p;
    };
    int*     gstart = (int*)alloc((size_t)N_GRAPHS * 4);
    int*     gend   = (int*)alloc((size_t)N_GRAPHS * 4);
    size_t   zero_bytes = o;                      // gstart+gend contiguous
    int*     cnt    = (int*)alloc((size_t)N_NODES * 4);
    int*     counts = (int*)alloc((size_t)NCHUNK * NBUCKET * 4);
    int*     offs   = (int*)alloc((size_t)NCHUNK * NBUCKET * 4);
    int*     total  = (int*)alloc((size_t)NBUCKET * 4);
    int*     basep  = (int*)alloc((size_t)NBUCKET * 4);
    uint32_t* ebuf  = (uint32_t*)alloc((size_t)N_EDGES * 4);
    int*     padded = (int*)alloc((size_t)N_NODES * PAD_CAP * 4);    // 12.8 MB
    ushort*  xb     = (ushort*)alloc((size_t)N_NODES * DIM * 2);
    ushort*  ha     = (ushort*)alloc((size_t)N_NODES * DIM * 2);
    ushort*  hb     = (ushort*)alloc((size_t)N_NODES * DIM * 2);
    float*   h3     = (float*)alloc((size_t)N_NODES * DIM * 4);
    ushort*  Wt     = (ushort*)alloc((size_t)3 * DIM * K2 * 2);
    (void)ws_size; (void)n_in; (void)in_sizes;

    hipMemsetAsync(base, 0, zero_bytes, stream);
    hipMemsetAsync(d_out, 0, (size_t)out_size * 4, stream);

    k_convert_x<<<(N_NODES * DIM / 4 + 255) / 256, 256, 0, stream>>>(x, xb);
    k_prep_w_all<<<(3 * DIM * K2 + 255) / 256, 256, 0, stream>>>(
        Wl[0], Wr[0], Wl[1], Wr[1], Wl[2], Wr[2], Wt);

    k_hist<<<NCHUNK, 256, 0, stream>>>(dst, counts);
    k_scan_col<<<NBUCKET, 256, 0, stream>>>(counts, offs, total);
    k_scan_total<<<1, 256, 0, stream>>>(total, basep);
    k_scatter<<<NCHUNK, 256, 0, stream>>>(src, dst, offs, basep, ebuf);
    k_build<<<NBUCKET, 256, 0, stream>>>(ebuf, total, basep, padded, cnt);
    k_sort_adj<<<(N_NODES + 3) / 4, 256, 0, stream>>>(padded, cnt);
    k_gbounds<<<(N_NODES + 255) / 256, 256, 0, stream>>>(batch, gstart, gend);

    // fused layers (one kernel each)
    k_layer<false><<<N_STRIPS, 256, 0, stream>>>(xb, padded, cnt, Wt,              bl[0], ha, nullptr);
    k_layer<false><<<N_STRIPS, 256, 0, stream>>>(ha, padded, cnt, Wt + DIM * K2,   bl[1], hb, nullptr);
    k_layer<true ><<<N_STRIPS, 256, 0, stream>>>(hb, padded, cnt, Wt + 2 * DIM * K2, bl[2], nullptr, h3);

    k_readout<<<(N_NODES + RO_ROWS - 1) / RO_ROWS, 128, 0, stream>>>(h3, batch, out);
    k_finalize<<<(N_GRAPHS * DIM + 255) / 256, 256, 0, stream>>>(out, gstart, gend);
}

// Round 4
// 349.445 us; speedup vs baseline: 1.0196x; 1.0196x over previous
//
#include <hip/hip_runtime.h>
#include <hip/hip_bf16.h>
#include <stdint.h>

#define N_NODES  50000
#define N_GRAPHS 256
#define DIM      128
#define N_EDGES  800000
#define K2       256            // fused K = [agg | h]
#define N_STRIPS (N_NODES / 16) // 3125, exact
#define PAD_CAP  64             // max degree slack (mean 16; fixed edge list, no overflow)
#define RO_ROWS  32             // readout rows per block

typedef __attribute__((ext_vector_type(8))) short  short8;
typedef __attribute__((ext_vector_type(4))) float  floatx4;
typedef __attribute__((ext_vector_type(4))) int    intx4;

__device__ __forceinline__ ushort f2bf(float f) {
    union { float f; uint32_t u; } c; c.f = f;
    uint32_t u = c.u;
    return (ushort)((u + 0x7fffu + ((u >> 16) & 1u)) >> 16);  // RNE
}
__device__ __forceinline__ float bf2f(ushort b) {
    union { uint32_t u; float f; } c; c.u = ((uint32_t)b) << 16;
    return c.f;
}

// ---------- fused prep: convert_x | prep_w | gbounds | cnt-zero | out-zero ----------
// Block ranges: [0,6250) convert, [6250,6634) prep_w, [6634,6830) gbounds,
// [6830,7026) cnt zero, [7026,7282) out zero. One dispatch replaces 3 kernels + 2 memsets.
#define MB_CONV 6250
#define MB_PREPW (MB_CONV + 384)
#define MB_GB   (MB_PREPW + 196)
#define MB_CNT  (MB_GB + 196)
#define MB_OUT  (MB_CNT + 256)
__global__ __launch_bounds__(256) void k_misc(const float* __restrict__ x, ushort* __restrict__ xb,
                                              const float* __restrict__ Wl0, const float* __restrict__ Wr0,
                                              const float* __restrict__ Wl1, const float* __restrict__ Wr1,
                                              const float* __restrict__ Wl2, const float* __restrict__ Wr2,
                                              ushort* __restrict__ Wt,
                                              const int* __restrict__ batch,
                                              int* __restrict__ gstart, int* __restrict__ gend,
                                              int* __restrict__ cnt, float* __restrict__ out) {
    int b = blockIdx.x, t = threadIdx.x;
    if (b < MB_CONV) {                       // fp32 x -> bf16 (float4 granularity)
        int i = b * 256 + t;                 // i < 1.6M exactly
        float4 v = ((const float4*)x)[i];
        uint32_t lo = (uint32_t)f2bf(v.x) | ((uint32_t)f2bf(v.y) << 16);
        uint32_t hi = (uint32_t)f2bf(v.z) | ((uint32_t)f2bf(v.w) << 16);
        ((uint2*)xb)[i] = make_uint2(lo, hi);
    } else if (b < MB_PREPW) {               // Wt[l][n][k] = bf16(k<128 ? Wl[k][n] : Wr[k-128][n])
        int i = (b - MB_CONV) * 256 + t;     // i < 98304 exactly
        int layer = i / (DIM * K2);
        int j = i % (DIM * K2);
        int n = j / K2, k = j % K2;
        const float* Wl = (layer == 0) ? Wl0 : (layer == 1) ? Wl1 : Wl2;
        const float* Wr = (layer == 0) ? Wr0 : (layer == 1) ? Wr1 : Wr2;
        float v = (k < DIM) ? Wl[k * DIM + n] : Wr[(k - DIM) * DIM + n];
        Wt[i] = f2bf(v);
    } else if (b < MB_GB) {                  // per-graph node ranges from sorted batch
        int i = (b - MB_PREPW) * 256 + t;
        if (i < N_NODES) {
            int g = batch[i];
            if (i == 0) gstart[g] = 0;
            int gn = (i + 1 < N_NODES) ? batch[i + 1] : -1;
            if (gn != g) {
                gend[g] = i + 1;
                if (gn >= 0) gstart[gn] = i + 1;
            }
        }
    } else if (b < MB_CNT) {                 // zero degree counters (pre-build)
        int i = (b - MB_GB) * 256 + t;
        if (i < N_NODES) cnt[i] = 0;
    } else {                                 // zero output (pre-readout atomics)
        int i = (b - MB_CNT) * 256 + t;
        if (i < N_GRAPHS * 2 * DIM) out[i] = 0.f;
    }
}

// ---------- direct adjacency build: one kernel, global atomics ----------
// Insertion order is nondeterministic, but k_sort_adj canonicalizes each list, so the
// final padded[] is a deterministic function of the edge multiset (PAD_CAP never hit:
// Poisson(16) tail at 64 is ~0).
__global__ __launch_bounds__(256) void k_build_direct(const int* __restrict__ src,
                                                      const int* __restrict__ dst,
                                                      int* __restrict__ cnt,
                                                      int* __restrict__ padded) {
    int i = blockIdx.x * 256 + threadIdx.x;
    if (i < N_EDGES) {
        int d = dst[i], s = src[i];
        int p = atomicAdd(&cnt[d], 1);
        if (p < PAD_CAP) padded[(size_t)d * PAD_CAP + p] = s;
    }
}

// ---------- canonicalize adjacency: bitonic sort each node's list across one wave ----------
__global__ __launch_bounds__(256) void k_sort_adj(int* __restrict__ padded,
                                                  const int* __restrict__ cnt) {
    int wid  = threadIdx.x >> 6;
    int lane = threadIdx.x & 63;
    int node = blockIdx.x * 4 + wid;
    if (node >= N_NODES) return;
    int deg = cnt[node];
    int m   = deg < PAD_CAP ? deg : PAD_CAP;
    int* lst = padded + (size_t)node * PAD_CAP;
    int v = (lane < m) ? lst[lane] : 0x7fffffff;   // pad sorts to the end
    #pragma unroll
    for (int k = 2; k <= 64; k <<= 1) {
        #pragma unroll
        for (int j = k >> 1; j > 0; j >>= 1) {
            int other  = __shfl_xor(v, j, 64);
            bool down  = (lane & k) != 0;
            bool lower = (lane & j) == 0;
            v = (lower ^ down) ? min(v, other) : max(v, other);
        }
    }
    if (lane < m) lst[lane] = v;                   // ascending neighbor ids
}

// ---------- fused SAGE layer: gather-mean into LDS, then MFMA (R1 structure + nt) ----------
// Phase 1: strip's neighbor lists staged to LDS (nontemporal — read-once stream, keep it
// out of L2 so gather rows of h stay resident); per wave, 4 nodes flattened into chunks
// of 16 edges, register double-buffered so chunk i+1's 16 row loads are in flight while
// chunk i accumulates (consume(i) needs only vmcnt(16) — never waits on i+1's loads).
// Phase 2: A = [LDS agg | global h] frags, B = Wt, 2 col-tiles/wave. Output stores are
// nontemporal (write-once stream; cross-kernel L2 retention is nil anyway).
template <bool OUT_F32>
__global__ __launch_bounds__(256) void k_layer(const ushort* __restrict__ h_in,
                                               const int* __restrict__ padded,
                                               const int* __restrict__ cnt,
                                               const ushort* __restrict__ Wt,
                                               const float* __restrict__ bias,
                                               ushort* __restrict__ out_bf,
                                               float* __restrict__ out_f) {
    __shared__ ushort sAgg[16 * DIM];              // 4 KB
    __shared__ int    sIdx[16 * PAD_CAP];          // 4 KB neighbor lists
    __shared__ int    sCnt[16];
    __shared__ int    sChl[4][17];                 // per-wave chunk list: q | (e0<<8)
    __shared__ int    sNch[4];

    int t    = threadIdx.x;
    int wid  = t >> 6;
    int lane = t & 63;
    int r0   = blockIdx.x * 16;
    const uint32_t* hw = (const uint32_t*)h_in;    // 64 dwords per row

    // ---- stage neighbor lists + degrees (coalesced, nontemporal: no L2 pollution) ----
    ((intx4*)sIdx)[t] = __builtin_nontemporal_load(
        ((const intx4*)(padded + (size_t)r0 * PAD_CAP)) + t);
    if (t < 16) sCnt[t] = cnt[r0 + t];
    __syncthreads();

    // ---- per-wave flattened chunk list (wave-uniform; lane 0 writes) ----
    if (lane == 0) {
        int n = 0;
        #pragma unroll
        for (int q = 0; q < 4; ++q) {
            int m = min(sCnt[wid * 4 + q], PAD_CAP);
            for (int e0 = 0; e0 < m; e0 += 16)
                sChl[wid][n++] = q | (e0 << 8);
        }
        sNch[wid] = n;
    }
    // zero agg rows for isolated nodes (no chunks emitted for them)
    #pragma unroll
    for (int q = 0; q < 4; ++q) {
        int node = wid * 4 + q;
        if (sCnt[node] == 0) ((uint32_t*)(sAgg + node * DIM))[lane] = 0u;
    }
    int nch = sNch[wid];

    float ax[4] = {0.f, 0.f, 0.f, 0.f};
    float ay[4] = {0.f, 0.f, 0.f, 0.f};
    uint32_t va[16], vb[16];                       // double-buffered gather rows

    auto issue = [&](int ci, uint32_t (&v)[16]) {
        int ch   = sChl[wid][ci];
        int q    = ch & 255, e0 = ch >> 8;
        int node = wid * 4 + q;
        int m    = min(sCnt[node], PAD_CAP);
        const int* lst = sIdx + node * PAD_CAP;
        #pragma unroll
        for (int k = 0; k < 16; ++k) {
            int ek = e0 + k;
            int id = lst[ek < m ? ek : m - 1];     // LDS broadcast; m>=1 here
            v[k] = hw[(size_t)id * 64 + lane];     // 16 row loads in flight
        }
    };
    auto consume = [&](int ci, uint32_t (&v)[16], bool isLast) {
        int ch   = sChl[wid][ci];
        int q    = ch & 255, e0 = ch >> 8;
        int node = wid * 4 + q;
        int deg  = sCnt[node];
        int m    = min(deg, PAD_CAP);
        #pragma unroll
        for (int k = 0; k < 16; ++k) {
            uint32_t w = (e0 + k < m) ? v[k] : 0u; // predicated tail (bf16 +0.0)
            ax[k & 3] += __uint_as_float(w << 16);
            ay[k & 3] += __uint_as_float(w & 0xffff0000u);
        }
        bool lastOfNode = isLast || ((sChl[wid][ci + 1] & 255) != q);
        if (lastOfNode) {
            float axs = (ax[0] + ax[1]) + (ax[2] + ax[3]);
            float ays = (ay[0] + ay[1]) + (ay[2] + ay[3]);
            float inv = 1.0f / (float)(deg > 0 ? deg : 1);
            uint32_t o = (uint32_t)f2bf(axs * inv) | ((uint32_t)f2bf(ays * inv) << 16);
            ((uint32_t*)(sAgg + node * DIM))[lane] = o;
            #pragma unroll
            for (int j = 0; j < 4; ++j) { ax[j] = 0.f; ay[j] = 0.f; }
        }
    };

    if (nch > 0) {
        issue(0, va);
        int i = 0;
        while (true) {
            bool hasB = (i + 1) < nch;
            if (hasB) issue(i + 1, vb);            // overlap: loads(i+1) || accumulate(i)
            consume(i, va, !hasB);
            if (!hasB) break;
            bool hasA = (i + 2) < nch;
            if (hasA) issue(i + 2, va);
            consume(i + 1, vb, !hasA);
            if (!hasA) break;
            i += 2;
        }
    }
    __syncthreads();

    // ---- phase 2: MFMA. A-frags: lane holds A[m=lane&15][k=quad*8+j] ----
    int row  = lane & 15;
    int quad = lane >> 4;
    short8 a[8];
    const ushort* srow = sAgg + row * DIM + quad * 8;
    #pragma unroll
    for (int ks = 0; ks < 4; ++ks) a[ks] = *(const short8*)(srow + ks * 32);  // LDS b128
    const ushort* hrow = h_in + (size_t)(r0 + row) * DIM + quad * 8;
    #pragma unroll
    for (int ks = 0; ks < 4; ++ks) a[4 + ks] = *(const short8*)(hrow + ks * 32);

    #pragma unroll
    for (int c = 0; c < 2; ++c) {
        int ct  = wid * 2 + c;                     // 4 waves x 2 = 8 col-tiles
        int col = ct * 16 + row;
        const ushort* wrow = Wt + (size_t)col * K2 + quad * 8;
        floatx4 acc = {0.f, 0.f, 0.f, 0.f};
        #pragma unroll
        for (int ks = 0; ks < 8; ++ks) {
            short8 b = *(const short8*)(wrow + ks * 32);
            acc = __builtin_amdgcn_mfma_f32_16x16x32_bf16(a[ks], b, acc, 0, 0, 0);
        }
        float bv = bias[col];
        #pragma unroll
        for (int r = 0; r < 4; ++r) {
            int m = r0 + quad * 4 + r;             // C/D: col=lane&15, row=quad*4+reg
            float v = acc[r] + bv;
            v = v > 0.f ? v : 0.f;
            if (OUT_F32) __builtin_nontemporal_store(v, &out_f[(size_t)m * DIM + col]);
            else         __builtin_nontemporal_store(f2bf(v), &out_bf[(size_t)m * DIM + col]);
        }
    }
}

// ---------- mean/max readout (batch sorted -> run-length flush) ----------
__global__ __launch_bounds__(128) void k_readout(const float* __restrict__ h,
                                                 const int* __restrict__ batch,
                                                 float* __restrict__ out) {
    int d  = threadIdx.x;                 // 0..127
    int n0 = blockIdx.x * RO_ROWS;
    int n1 = min(n0 + RO_ROWS, N_NODES);
    int cur = -1; float sum = 0.f, mx = 0.f;
    for (int i = n0; i < n1; ++i) {
        int g = batch[i];                 // block-uniform
        if (g != cur) {
            if (cur >= 0) {
                atomicAdd(&out[cur * 2 * DIM + d], sum);
                atomicMax((int*)&out[cur * 2 * DIM + DIM + d], __float_as_int(mx));
            }
            cur = g; sum = 0.f; mx = 0.f;
        }
        float v = __builtin_nontemporal_load(&h[(size_t)i * DIM + d]);
        sum += v; mx = fmaxf(mx, v);
    }
    if (cur >= 0) {
        atomicAdd(&out[cur * 2 * DIM + d], sum);
        atomicMax((int*)&out[cur * 2 * DIM + DIM + d], __float_as_int(mx));
    }
}

__global__ __launch_bounds__(256) void k_finalize(float* __restrict__ out,
                                                  const int* __restrict__ gstart,
                                                  const int* __restrict__ gend) {
    int i = blockIdx.x * 256 + threadIdx.x;
    if (i < N_GRAPHS * DIM) {
        int g = i / DIM, d = i % DIM;
        int c = gend[g] - gstart[g];
        out[g * 2 * DIM + d] /= (float)(c > 0 ? c : 1);
    }
}

extern "C" void kernel_launch(void* const* d_in, const int* in_sizes, int n_in,
                              void* d_out, int out_size, void* d_ws, size_t ws_size,
                              hipStream_t stream) {
    const float* x     = (const float*)d_in[0];
    const int*   ei    = (const int*)d_in[1];
    const int*   src   = ei;
    const int*   dst   = ei + N_EDGES;
    const int*   batch = (const int*)d_in[2];
    const float* Wl[3] = {(const float*)d_in[3], (const float*)d_in[6], (const float*)d_in[9]};
    const float* bl[3] = {(const float*)d_in[4], (const float*)d_in[7], (const float*)d_in[10]};
    const float* Wr[3] = {(const float*)d_in[5], (const float*)d_in[8], (const float*)d_in[11]};
    float* out = (float*)d_out;

    char* base = (char*)d_ws;
    size_t o = 0;
    auto alloc = [&](size_t b) -> char* {
        char* p = base + o;
        o = (o + b + 255) & ~(size_t)255;
        return p;
    };
    int*     gstart = (int*)alloc((size_t)N_GRAPHS * 4);
    int*     gend   = (int*)alloc((size_t)N_GRAPHS * 4);
    int*     cnt    = (int*)alloc((size_t)N_NODES * 4);
    int*     padded = (int*)alloc((size_t)N_NODES * PAD_CAP * 4);    // 12.8 MB
    ushort*  xb     = (ushort*)alloc((size_t)N_NODES * DIM * 2);
    ushort*  ha     = (ushort*)alloc((size_t)N_NODES * DIM * 2);
    ushort*  hb     = (ushort*)alloc((size_t)N_NODES * DIM * 2);
    float*   h3     = (float*)alloc((size_t)N_NODES * DIM * 4);
    ushort*  Wt     = (ushort*)alloc((size_t)3 * DIM * K2 * 2);
    (void)ws_size; (void)n_in; (void)in_sizes; (void)out_size;

    // one fused prep dispatch: convert | weights | gbounds | cnt=0 | out=0
    k_misc<<<MB_OUT, 256, 0, stream>>>(x, xb, Wl[0], Wr[0], Wl[1], Wr[1], Wl[2], Wr[2],
                                       Wt, batch, gstart, gend, cnt, out);
    k_build_direct<<<(N_EDGES + 255) / 256, 256, 0, stream>>>(src, dst, cnt, padded);
    k_sort_adj<<<(N_NODES + 3) / 4, 256, 0, stream>>>(padded, cnt);

    // fused layers (one kernel each)
    k_layer<false><<<N_STRIPS, 256, 0, stream>>>(xb, padded, cnt, Wt,                bl[0], ha, nullptr);
    k_layer<false><<<N_STRIPS, 256, 0, stream>>>(ha, padded, cnt, Wt + DIM * K2,     bl[1], hb, nullptr);
    k_layer<true ><<<N_STRIPS, 256, 0, stream>>>(hb, padded, cnt, Wt + 2 * DIM * K2, bl[2], nullptr, h3);

    k_readout<<<(N_NODES + RO_ROWS - 1) / RO_ROWS, 128, 0, stream>>>(h3, batch, out);
    k_finalize<<<(N_GRAPHS * DIM + 255) / 256, 256, 0, stream>>>(out, gstart, gend);
}

// Round 5
// 327.376 us; speedup vs baseline: 1.0883x; 1.0674x over previous
//
#include <hip/hip_runtime.h>
#include <hip/hip_bf16.h>
#include <stdint.h>

#define N_NODES  50000
#define N_GRAPHS 256
#define DIM      128
#define N_EDGES  800000
#define K2       256            // fused K = [agg | h]
#define N_STRIPS (N_NODES / 16) // 3125, exact
#define PAD_CAP  64             // max degree slack (mean 16; fixed edge list, no overflow)

typedef __attribute__((ext_vector_type(8))) short  short8;
typedef __attribute__((ext_vector_type(4))) float  floatx4;
typedef __attribute__((ext_vector_type(4))) int    intx4;

__device__ __forceinline__ ushort f2bf(float f) {
    union { float f; uint32_t u; } c; c.f = f;
    uint32_t u = c.u;
    return (ushort)((u + 0x7fffu + ((u >> 16) & 1u)) >> 16);  // RNE
}

// ---------- fused prep: convert_x | prep_w | gbounds | cnt-zero | out-zero ----------
#define MB_CONV 6250
#define MB_PREPW (MB_CONV + 384)
#define MB_GB   (MB_PREPW + 196)
#define MB_CNT  (MB_GB + 196)
#define MB_OUT  (MB_CNT + 256)
__global__ __launch_bounds__(256) void k_misc(const float* __restrict__ x, ushort* __restrict__ xb,
                                              const float* __restrict__ Wl0, const float* __restrict__ Wr0,
                                              const float* __restrict__ Wl1, const float* __restrict__ Wr1,
                                              const float* __restrict__ Wl2, const float* __restrict__ Wr2,
                                              ushort* __restrict__ Wt,
                                              const int* __restrict__ batch,
                                              int* __restrict__ gstart, int* __restrict__ gend,
                                              int* __restrict__ cnt, float* __restrict__ out) {
    int b = blockIdx.x, t = threadIdx.x;
    if (b < MB_CONV) {                       // fp32 x -> bf16 (float4 granularity)
        int i = b * 256 + t;                 // i < 1.6M exactly
        float4 v = ((const float4*)x)[i];
        uint32_t lo = (uint32_t)f2bf(v.x) | ((uint32_t)f2bf(v.y) << 16);
        uint32_t hi = (uint32_t)f2bf(v.z) | ((uint32_t)f2bf(v.w) << 16);
        ((uint2*)xb)[i] = make_uint2(lo, hi);
    } else if (b < MB_PREPW) {               // Wt[l][n][k] = bf16(k<128 ? Wl[k][n] : Wr[k-128][n])
        int i = (b - MB_CONV) * 256 + t;     // i < 98304 exactly
        int layer = i / (DIM * K2);
        int j = i % (DIM * K2);
        int n = j / K2, k = j % K2;
        const float* Wl = (layer == 0) ? Wl0 : (layer == 1) ? Wl1 : Wl2;
        const float* Wr = (layer == 0) ? Wr0 : (layer == 1) ? Wr1 : Wr2;
        float v = (k < DIM) ? Wl[k * DIM + n] : Wr[(k - DIM) * DIM + n];
        Wt[i] = f2bf(v);
    } else if (b < MB_GB) {                  // per-graph node ranges from sorted batch
        int i = (b - MB_PREPW) * 256 + t;
        if (i < N_NODES) {
            int g = batch[i];
            if (i == 0) gstart[g] = 0;
            int gn = (i + 1 < N_NODES) ? batch[i + 1] : -1;
            if (gn != g) {
                gend[g] = i + 1;
                if (gn >= 0) gstart[gn] = i + 1;
            }
        }
    } else if (b < MB_CNT) {                 // zero degree counters (pre-build)
        int i = (b - MB_GB) * 256 + t;
        if (i < N_NODES) cnt[i] = 0;
    } else {                                 // zero output (pre-readout atomics)
        int i = (b - MB_CNT) * 256 + t;
        if (i < N_GRAPHS * 2 * DIM) out[i] = 0.f;
    }
}

// ---------- direct adjacency build: one kernel, global atomics ----------
// Insertion order is nondeterministic; k_layer<0> sorts each list before any use, so
// every consumer sees a canonical (ascending) list — deterministic given the edge set.
__global__ __launch_bounds__(256) void k_build_direct(const int* __restrict__ src,
                                                      const int* __restrict__ dst,
                                                      int* __restrict__ cnt,
                                                      int* __restrict__ padded) {
    int i = blockIdx.x * 256 + threadIdx.x;
    if (i < N_EDGES) {
        int d = dst[i], s = src[i];
        int p = atomicAdd(&cnt[d], 1);
        if (p < PAD_CAP) padded[(size_t)d * PAD_CAP + p] = s;
    }
}

// ---------- fused SAGE layer ----------
// MODE 0: sorts each node's neighbor list in-wave (bitonic via shfl_xor) right after
//         LDS staging, uses it, and writes the canonical list back for layers 1-2.
//         Replaces the standalone k_sort_adj pass (25.6 MB r+w + dispatch).
// MODE 1: plain middle layer (bf16 out).
// MODE 2: last layer; keeps its 16 f32 output rows in an 8 KB LDS tile and does the
//         per-graph mean/max readout in-block (~280 atomics). Replaces the 25.6 MB h3
//         store AND the 25.6 MB k_readout re-read + dispatch.
// Phase 1 gather: R1 register double-buffer (chunk i+1's 16 row loads in flight while
// chunk i accumulates). Phase 2: A = [LDS agg | global h], B = Wt, 2 col-tiles/wave.
template <int MODE>
__global__ __launch_bounds__(256) void k_layer(const ushort* __restrict__ h_in,
                                               int* __restrict__ padded,
                                               const int* __restrict__ cnt,
                                               const ushort* __restrict__ Wt,
                                               const float* __restrict__ bias,
                                               ushort* __restrict__ out_bf,
                                               const int* __restrict__ batch,
                                               float* __restrict__ gout) {
    __shared__ ushort sAgg[16 * DIM];              // 4 KB
    __shared__ int    sIdx[16 * PAD_CAP];          // 4 KB neighbor lists
    __shared__ int    sCnt[16];
    __shared__ int    sChl[4][17];                 // per-wave chunk list: q | (e0<<8)
    __shared__ int    sNch[4];
    __shared__ int    sGb[(MODE == 2) ? 16 : 1];   // per-row graph ids (MODE 2)
    __shared__ float  hTile[(MODE == 2) ? 16 * DIM : 1];  // 8 KB f32 out tile (MODE 2)

    int t    = threadIdx.x;
    int wid  = t >> 6;
    int lane = t & 63;
    int r0   = blockIdx.x * 16;
    const uint32_t* hw = (const uint32_t*)h_in;    // 64 dwords per row

    // ---- stage neighbor lists + degrees (coalesced, nontemporal) ----
    ((intx4*)sIdx)[t] = __builtin_nontemporal_load(
        ((const intx4*)(padded + (size_t)r0 * PAD_CAP)) + t);
    if (t < 16) sCnt[t] = cnt[r0 + t];
    if (MODE == 2 && t >= 16 && t < 32) sGb[t - 16] = batch[r0 + t - 16];
    __syncthreads();

    // ---- MODE 0: canonicalize lists in-wave (4 sequential 64-lane bitonics) ----
    if (MODE == 0) {
        #pragma unroll
        for (int q = 0; q < 4; ++q) {
            int nl  = wid * 4 + q;
            int m   = min(sCnt[nl], PAD_CAP);
            int* lst = sIdx + nl * PAD_CAP;
            int v = (lane < m) ? lst[lane] : 0x7fffffff;   // pads sort to the end
            #pragma unroll
            for (int k = 2; k <= 64; k <<= 1) {
                #pragma unroll
                for (int j = k >> 1; j > 0; j >>= 1) {
                    int other  = __shfl_xor(v, j, 64);
                    bool down  = (lane & k) != 0;
                    bool lower = (lane & j) == 0;
                    v = (lower ^ down) ? min(v, other) : max(v, other);
                }
            }
            if (lane < m) {
                lst[lane] = v;                             // wave-local LDS, no barrier
                __builtin_nontemporal_store(v,             // canonical list for layers 1-2
                    &padded[(size_t)(r0 + nl) * PAD_CAP + lane]);
            }
        }
    }

    // ---- per-wave flattened chunk list (wave-uniform; lane 0 writes) ----
    if (lane == 0) {
        int n = 0;
        #pragma unroll
        for (int q = 0; q < 4; ++q) {
            int m = min(sCnt[wid * 4 + q], PAD_CAP);
            for (int e0 = 0; e0 < m; e0 += 16)
                sChl[wid][n++] = q | (e0 << 8);
        }
        sNch[wid] = n;
    }
    // zero agg rows for isolated nodes (no chunks emitted for them)
    #pragma unroll
    for (int q = 0; q < 4; ++q) {
        int node = wid * 4 + q;
        if (sCnt[node] == 0) ((uint32_t*)(sAgg + node * DIM))[lane] = 0u;
    }
    int nch = sNch[wid];

    float ax[4] = {0.f, 0.f, 0.f, 0.f};
    float ay[4] = {0.f, 0.f, 0.f, 0.f};
    uint32_t va[16], vb[16];                       // double-buffered gather rows

    auto issue = [&](int ci, uint32_t (&v)[16]) {
        int ch   = sChl[wid][ci];
        int q    = ch & 255, e0 = ch >> 8;
        int node = wid * 4 + q;
        int m    = min(sCnt[node], PAD_CAP);
        const int* lst = sIdx + node * PAD_CAP;
        #pragma unroll
        for (int k = 0; k < 16; ++k) {
            int ek = e0 + k;
            int id = lst[ek < m ? ek : m - 1];     // LDS broadcast; m>=1 here
            v[k] = hw[(size_t)id * 64 + lane];     // 16 row loads in flight
        }
    };
    auto consume = [&](int ci, uint32_t (&v)[16], bool isLast) {
        int ch   = sChl[wid][ci];
        int q    = ch & 255, e0 = ch >> 8;
        int node = wid * 4 + q;
        int deg  = sCnt[node];
        int m    = min(deg, PAD_CAP);
        #pragma unroll
        for (int k = 0; k < 16; ++k) {
            uint32_t w = (e0 + k < m) ? v[k] : 0u; // predicated tail (bf16 +0.0)
            ax[k & 3] += __uint_as_float(w << 16);
            ay[k & 3] += __uint_as_float(w & 0xffff0000u);
        }
        bool lastOfNode = isLast || ((sChl[wid][ci + 1] & 255) != q);
        if (lastOfNode) {
            float axs = (ax[0] + ax[1]) + (ax[2] + ax[3]);
            float ays = (ay[0] + ay[1]) + (ay[2] + ay[3]);
            float inv = 1.0f / (float)(deg > 0 ? deg : 1);
            uint32_t o = (uint32_t)f2bf(axs * inv) | ((uint32_t)f2bf(ays * inv) << 16);
            ((uint32_t*)(sAgg + node * DIM))[lane] = o;
            #pragma unroll
            for (int j = 0; j < 4; ++j) { ax[j] = 0.f; ay[j] = 0.f; }
        }
    };

    if (nch > 0) {
        issue(0, va);
        int i = 0;
        while (true) {
            bool hasB = (i + 1) < nch;
            if (hasB) issue(i + 1, vb);            // overlap: loads(i+1) || accumulate(i)
            consume(i, va, !hasB);
            if (!hasB) break;
            bool hasA = (i + 2) < nch;
            if (hasA) issue(i + 2, va);
            consume(i + 1, vb, !hasA);
            if (!hasA) break;
            i += 2;
        }
    }
    __syncthreads();

    // ---- phase 2: MFMA. A-frags: lane holds A[m=lane&15][k=quad*8+j] ----
    int row  = lane & 15;
    int quad = lane >> 4;
    short8 a[8];
    const ushort* srow = sAgg + row * DIM + quad * 8;
    #pragma unroll
    for (int ks = 0; ks < 4; ++ks) a[ks] = *(const short8*)(srow + ks * 32);  // LDS b128
    const ushort* hrow = h_in + (size_t)(r0 + row) * DIM + quad * 8;
    #pragma unroll
    for (int ks = 0; ks < 4; ++ks) a[4 + ks] = *(const short8*)(hrow + ks * 32);

    #pragma unroll
    for (int c = 0; c < 2; ++c) {
        int ct  = wid * 2 + c;                     // 4 waves x 2 = 8 col-tiles
        int col = ct * 16 + row;
        const ushort* wrow = Wt + (size_t)col * K2 + quad * 8;
        floatx4 acc = {0.f, 0.f, 0.f, 0.f};
        #pragma unroll
        for (int ks = 0; ks < 8; ++ks) {
            short8 b = *(const short8*)(wrow + ks * 32);
            acc = __builtin_amdgcn_mfma_f32_16x16x32_bf16(a[ks], b, acc, 0, 0, 0);
        }
        float bv = bias[col];
        #pragma unroll
        for (int r = 0; r < 4; ++r) {
            int m = r0 + quad * 4 + r;             // C/D: col=lane&15, row=quad*4+reg
            float v = acc[r] + bv;
            v = v > 0.f ? v : 0.f;
            if (MODE < 2) __builtin_nontemporal_store(f2bf(v), &out_bf[(size_t)m * DIM + col]);
            else          hTile[(quad * 4 + r) * DIM + col] = v;
        }
    }

    // ---- MODE 2: in-block mean/max readout (batch sorted -> run-length flush) ----
    if (MODE == 2) {
        __syncthreads();
        int d     = t & 127;
        bool doMax = t >= 128;                     // threads 0-127: sum; 128-255: max
        float s = 0.f, mx = 0.f;
        int cur = sGb[0];
        #pragma unroll
        for (int m = 0; m < 16; ++m) {
            int g = sGb[m];
            if (g != cur) {
                if (doMax) atomicMax((int*)&gout[cur * 2 * DIM + DIM + d], __float_as_int(mx));
                else       atomicAdd(&gout[cur * 2 * DIM + d], s);
                cur = g; s = 0.f; mx = 0.f;
            }
            float v = hTile[m * DIM + d];
            s += v; mx = fmaxf(mx, v);
        }
        if (doMax) atomicMax((int*)&gout[cur * 2 * DIM + DIM + d], __float_as_int(mx));
        else       atomicAdd(&gout[cur * 2 * DIM + d], s);
    }
}

__global__ __launch_bounds__(256) void k_finalize(float* __restrict__ out,
                                                  const int* __restrict__ gstart,
                                                  const int* __restrict__ gend) {
    int i = blockIdx.x * 256 + threadIdx.x;
    if (i < N_GRAPHS * DIM) {
        int g = i / DIM, d = i % DIM;
        int c = gend[g] - gstart[g];
        out[g * 2 * DIM + d] /= (float)(c > 0 ? c : 1);
    }
}

extern "C" void kernel_launch(void* const* d_in, const int* in_sizes, int n_in,
                              void* d_out, int out_size, void* d_ws, size_t ws_size,
                              hipStream_t stream) {
    const float* x     = (const float*)d_in[0];
    const int*   ei    = (const int*)d_in[1];
    const int*   src   = ei;
    const int*   dst   = ei + N_EDGES;
    const int*   batch = (const int*)d_in[2];
    const float* Wl[3] = {(const float*)d_in[3], (const float*)d_in[6], (const float*)d_in[9]};
    const float* bl[3] = {(const float*)d_in[4], (const float*)d_in[7], (const float*)d_in[10]};
    const float* Wr[3] = {(const float*)d_in[5], (const float*)d_in[8], (const float*)d_in[11]};
    float* out = (float*)d_out;

    char* base = (char*)d_ws;
    size_t o = 0;
    auto alloc = [&](size_t b) -> char* {
        char* p = base + o;
        o = (o + b + 255) & ~(size_t)255;
        return p;
    };
    int*     gstart = (int*)alloc((size_t)N_GRAPHS * 4);
    int*     gend   = (int*)alloc((size_t)N_GRAPHS * 4);
    int*     cnt    = (int*)alloc((size_t)N_NODES * 4);
    int*     padded = (int*)alloc((size_t)N_NODES * PAD_CAP * 4);    // 12.8 MB
    ushort*  xb     = (ushort*)alloc((size_t)N_NODES * DIM * 2);
    ushort*  ha     = (ushort*)alloc((size_t)N_NODES * DIM * 2);
    ushort*  hb     = (ushort*)alloc((size_t)N_NODES * DIM * 2);
    ushort*  Wt     = (ushort*)alloc((size_t)3 * DIM * K2 * 2);
    (void)ws_size; (void)n_in; (void)in_sizes; (void)out_size;

    // 6 dispatches total
    k_misc<<<MB_OUT, 256, 0, stream>>>(x, xb, Wl[0], Wr[0], Wl[1], Wr[1], Wl[2], Wr[2],
                                       Wt, batch, gstart, gend, cnt, out);
    k_build_direct<<<(N_EDGES + 255) / 256, 256, 0, stream>>>(src, dst, cnt, padded);

    k_layer<0><<<N_STRIPS, 256, 0, stream>>>(xb, padded, cnt, Wt,                bl[0], ha, batch, out);
    k_layer<1><<<N_STRIPS, 256, 0, stream>>>(ha, padded, cnt, Wt + DIM * K2,     bl[1], hb, batch, out);
    k_layer<2><<<N_STRIPS, 256, 0, stream>>>(hb, padded, cnt, Wt + 2 * DIM * K2, bl[2], nullptr, batch, out);

    k_finalize<<<(N_GRAPHS * DIM + 255) / 256, 256, 0, stream>>>(out, gstart, gend);
}